// Round 1
// baseline (135.209 us; speedup 1.0000x reference)
//
#include <hip/hip_runtime.h>
#include <math.h>

// Fused GAT forward: scores -> edge softmax per dst row -> weighted gather-sum.
// One 64-lane wave per destination node.
//   Score phase : lane = h*16 + e          (H=4 heads x DEG=16 edges = 64)
//   Aggr  phase : lane = h*16 + dpair      (4 heads x 16 float2 = 128 floats)
// Per edge, the whole wave reads in_feat[src][ : ][ : ] = 512 contiguous bytes
// (float2 per lane) -> perfectly coalesced gather. No LDS needed; alpha/col
// broadcast via __shfl within the wave.

#define GAT_H 4
#define GAT_D 32
#define GAT_DEG 16
#define GAT_NEG_SLOPE 0.2f

__global__ __launch_bounds__(256, 4) void gat_fused_kernel(
    const float* __restrict__ attn_row,    // [N,H]
    const float* __restrict__ attn_col,    // [N,H]
    const float* __restrict__ in_feat,     // [N,H,D]
    const int*   __restrict__ row_indptr,  // [N+1]
    const int*   __restrict__ col_indices, // [E]
    float*       __restrict__ out,         // [N,H,D]
    int n)
{
    const int wave_id = (int)((blockIdx.x * (unsigned)blockDim.x + threadIdx.x) >> 6);
    const int lane    = threadIdx.x & 63;
    if (wave_id >= n) return;
    const int i = wave_id;

    const int start = row_indptr[i];
    const int deg   = row_indptr[i + 1] - start;   // == 16 for this problem

    // ---------------- score phase: lane = h*16 + e ----------------
    const int e = lane & 15;
    const int h = lane >> 4;

    float s    = -INFINITY;
    int   colv = 0;
    if (e < deg) {
        colv = col_indices[start + e];
        const float ar = attn_row[i * GAT_H + h];
        const float ac = attn_col[colv * GAT_H + h];
        const float x  = ar + ac;
        s = (x > 0.0f) ? x : GAT_NEG_SLOPE * x;
    }

    // max over the 16 edges of this head (xor masks stay inside the group)
    float m = s;
    #pragma unroll
    for (int off = 1; off < 16; off <<= 1)
        m = fmaxf(m, __shfl_xor(m, off));

    float ex = (e < deg) ? __expf(s - m) : 0.0f;

    float denom = ex;
    #pragma unroll
    for (int off = 1; off < 16; off <<= 1)
        denom += __shfl_xor(denom, off);

    const float alpha = ex / denom;

    // ---------------- aggregation phase: lane = h*16 + dpair ----------------
    // lane l covers head (l>>4), features d0 = 2*(l&15), d0+1.
    // Offset within a node row: (l>>4)*32 + 2*(l&15) -> lanes 0..63 cover
    // floats 0..127 contiguously.
    const int d0   = (lane & 15) * 2;
    const int base = lane & 48;   // first lane of my 16-lane (head) group

    float accx = 0.0f, accy = 0.0f;
    #pragma unroll
    for (int k = 0; k < GAT_DEG; ++k) {
        const int   idx = __shfl(colv,  base + k);   // src node of edge k
        const float a   = __shfl(alpha, base + k);   // alpha[e=k][my head]
        const float2 f  = *reinterpret_cast<const float2*>(
            &in_feat[((long)idx * GAT_H + h) * GAT_D + d0]);
        accx = fmaf(a, f.x, accx);
        accy = fmaf(a, f.y, accy);
    }

    *reinterpret_cast<float2*>(&out[((long)i * GAT_H + h) * GAT_D + d0]) =
        make_float2(accx, accy);
}

extern "C" void kernel_launch(void* const* d_in, const int* in_sizes, int n_in,
                              void* d_out, int out_size, void* d_ws, size_t ws_size,
                              hipStream_t stream) {
    const float* attn_row    = (const float*)d_in[0];
    const float* attn_col    = (const float*)d_in[1];
    const float* in_feat     = (const float*)d_in[2];
    const int*   row_indptr  = (const int*)d_in[3];
    const int*   col_indices = (const int*)d_in[4];
    float*       out         = (float*)d_out;

    const int n = in_sizes[0] / GAT_H;              // N nodes (attn_row is [N,H])

    const int threads = 256;                        // 4 waves = 4 nodes / block
    const int nodes_per_block = threads / 64;
    const int blocks = (n + nodes_per_block - 1) / nodes_per_block;

    gat_fused_kernel<<<blocks, threads, 0, stream>>>(
        attn_row, attn_col, in_feat, row_indptr, col_indices, out, n);
}